// Round 13
// baseline (459.067 us; speedup 1.0000x reference)
//
#include <hip/hip_runtime.h>

// VQ-VAE VectorQuantizer: fp16 hi/lo 3-term MFMA distance + exact fp32 fallback.
// z: (32,64,64,64) NCHW fp32; codebook: (1024,64) fp32.
// d_out: [0]=loss, [1..]=z_q (NCHW).
//
// R21 (from R20 post-mortem): barrier-removal (R20) LOST to LDS-staging ->
// barrier theory dead. R15 (best total, 159.7 = 91 main + 5 fix + ~64 fixed)
// runs at 2 waves/SIMD (LDS 72KB -> 2 blocks/CU): MFMA pipe 20us + VALU 30us
// vs 91us wall = latency-hiding gap. This round = R15 with DOUBLED occupancy:
//  - CHUNK 128->64 (combined hi|lo chunk-major): dbuf 64->32KB, LDS ~37.5KB
//    -> 4 blocks/CU, 16 waves/CU (4/SIMD, 2x R15).
//  - __launch_bounds__(256,4): VGPR cap 128; R15 measured 116 -> no spill.
//  - barriers 8->16/block (R14 priced ~4us) -- occupancy buys more.
// Everything else VERBATIM R15: 3-term fp16 hi/lo (err~1e-4, TAU=1e-3 ->
// n~250), 512 blocks x 256 queries, 4 t-tiles/wave, batched flag atomics,
// per-block loss partials, R12-proven vq_fix + done_cnt finalize.

#define CB_N   1024
#define KDIM   64
#define HWD    4096
#define CHW    (KDIM * HWD)
#define NQ     131072
#define TOTALF 8388608.0f
#define TAU    1.0e-3f
#define FCAP   16384
#define CHUNK  64             // codes per LDS chunk
#define NCHUNK (CB_N / CHUNK) // 16
#define PLSTR  (CHUNK * KDIM) // u16 stride between hi and lo planes (4096)
#define NBLK   512            // vq_main grid

typedef __attribute__((ext_vector_type(8))) _Float16 half8;
typedef __attribute__((ext_vector_type(4))) float    f32x4;

// async 16B/lane global->LDS copy (wave-uniform contiguous; m97 pattern)
__device__ __forceinline__ void gload_lds16(const void* g, void* l) {
    __builtin_amdgcn_global_load_lds(
        (const __attribute__((address_space(1))) unsigned int*)g,
        (__attribute__((address_space(3))) unsigned int*)l,
        16, 0, 0);
}

// ---------- ws layout (byte offsets) ----------
// 0: loss_adj  4: flag_cnt  8: done_cnt
// 128:    loss_part f32[512]
// 4224:   norms     f32[1024]
// 8320:   cbx       u16[16][2][64][64]  (fp16 hi|lo, chunk-major, rotate-swz)
// 270464: flag_q i32[FCAP]  336000: flag_m1 f32[FCAP]  401536: flag_idx i32[FCAP]

// ---------------- prep: fp16 hi/lo split, combined layout, norms ------------
__global__ void vq_prep(const float* __restrict__ cb,
                        float* __restrict__ norms,
                        unsigned short* __restrict__ cbx,
                        float* __restrict__ loss_adj,
                        int* __restrict__ flag_cnt,
                        int* __restrict__ done_cnt) {
    const int tid = blockIdx.x * 256 + threadIdx.x;
    if (tid == 0) *loss_adj = 0.0f;
    if (tid == 1) *flag_cnt = 0;
    if (tid == 2) *done_cnt = 0;
    const int j  = tid >> 2;
    const int s2 = tid & 3;

    const int chunk = j >> 6;         // code's chunk (64 codes each)
    const int row   = j & 63;         // row within chunk
    unsigned short* hi = cbx + ((size_t)chunk * 2 + 0) * PLSTR + row * KDIM;
    unsigned short* lo = cbx + ((size_t)chunk * 2 + 1) * PLSTR + row * KDIM;

    const float4* r4 = (const float4*)(cb + (size_t)j * KDIM);
    float s_norm = 0.0f;
    #pragma unroll
    for (int seg8 = 0; seg8 < 2; ++seg8) {
        const int s = s2 * 2 + seg8;
        float4 v0 = r4[s * 2 + 0];
        float4 v1 = r4[s * 2 + 1];
        float e[8] = {v0.x, v0.y, v0.z, v0.w, v1.x, v1.y, v1.z, v1.w};
        unsigned hh[4], ll[4];
        #pragma unroll
        for (int c = 0; c < 8; ++c) {
            float x = e[c];
            s_norm = fmaf(x, x, s_norm);
            union { _Float16 h; unsigned short u; } ch, cl;
            ch.h = (_Float16)x;                       // RNE fp16 hi
            cl.h = (_Float16)(x - (float)ch.h);       // RNE fp16 lo
            if ((c & 1) == 0) { hh[c >> 1] = ch.u;               ll[c >> 1] = cl.u; }
            else              { hh[c >> 1] |= ((unsigned)ch.u) << 16;
                                ll[c >> 1] |= ((unsigned)cl.u) << 16; }
        }
        const int p = (s + j) & 7;                    // bank-deconflict rotate
        *(uint4*)(hi + p * 8) = make_uint4(hh[0], hh[1], hh[2], hh[3]);
        *(uint4*)(lo + p * 8) = make_uint4(ll[0], ll[1], ll[2], ll[3]);
    }
    s_norm += __shfl_xor(s_norm, 1, 64);
    s_norm += __shfl_xor(s_norm, 2, 64);
    if (s2 == 0) norms[j] = s_norm;
}

// ---------------- main ------------------------------------------------------
__global__ __launch_bounds__(256, 4) void vq_main(
        const float* __restrict__ z,
        const float* __restrict__ cb,
        const unsigned short* __restrict__ cbx,
        const float* __restrict__ norms,
        float* __restrict__ out,
        float* __restrict__ loss_part,
        int* __restrict__ flag_q,
        float* __restrict__ flag_m1,
        int* __restrict__ flag_idx,
        int* __restrict__ flag_cnt) {
    __shared__ float          norms_s[CB_N];             // 4 KB
    __shared__ unsigned short bx_s[2][2 * PLSTR];        // 2 x 16 KB (dbuf, hi|lo)
    __shared__ float          zn_s[256];
    __shared__ int            idx_s[256];
    __shared__ float          wsum_s[4];

    const int tid  = threadIdx.x;
    const int w    = tid >> 6;
    const int lane = tid & 63;
    const int quad = lane >> 4;
    const int l16  = lane & 15;
    const int qb   = blockIdx.x * 256;     // block's 256 queries (same batch b)
    const int b    = qb >> 12;
    const int hw0  = qb & 4095;
    const int ch0  = blockIdx.x & (NCHUNK - 1);   // de-phase chunk start

    // ---- issue stage of chunk 0 FIRST (flies under the z-read prologue)
    {
        const char* g = (const char*)cbx + (size_t)ch0 * (2 * PLSTR * 2);
        #pragma unroll
        for (int i = 0; i < 4; ++i) {
            const int off = (w * 4 + i) * 1024 + lane * 16;
            gload_lds16(g + off, (char*)&bx_s[0][0] + off);
        }
    }

    // ---- stage all code norms into LDS
    *(float4*)(norms_s + tid * 4) = *(const float4*)(norms + tid * 4);

    // ---- stage A-frags: wave w owns queries [64w, 64w+64); 4 tiles of 16.
    const float* zbase = z + (size_t)b * CHW + hw0 + 64 * w;
    half8 ah[4][2], al[4][2];
    float znp[4] = {0.f, 0.f, 0.f, 0.f};
    #pragma unroll
    for (int t = 0; t < 4; ++t)
        #pragma unroll
        for (int ks = 0; ks < 2; ++ks)
            #pragma unroll
            for (int j = 0; j < 8; ++j) {
                float v = zbase[(size_t)(ks * 32 + quad * 8 + j) * HWD + t * 16 + l16];
                znp[t] = fmaf(v, v, znp[t]);
                float s = -2.0f * v;
                _Float16 h = (_Float16)s;             // RNE fp16 hi
                ah[t][ks][j] = h;
                al[t][ks][j] = (_Float16)(s - (float)h);   // lo
            }
    #pragma unroll
    for (int t = 0; t < 4; ++t) {
        znp[t] += __shfl_xor(znp[t], 16, 64);
        znp[t] += __shfl_xor(znp[t], 32, 64);
    }
    if (lane < 16)
        #pragma unroll
        for (int t = 0; t < 4; ++t)
            zn_s[64 * w + t * 16 + lane] = znp[t];

    float m1[4][4], m2[4][4];
    int   i1[4][4];
    #pragma unroll
    for (int t = 0; t < 4; ++t)
        #pragma unroll
        for (int r = 0; r < 4; ++r) { m1[t][r] = 3.4e38f; m2[t][r] = 3.4e38f; i1[t][r] = 0; }

    // loop-invariant swizzled segment offsets (ks=0 / ks=1)
    const int p0 = ((quad + l16) & 7) * 8;
    const int p1 = ((4 + quad + l16) & 7) * 8;

    f32x4 bank[2][4];               // [tile-parity][t] -- deferred tracking
    #pragma unroll
    for (int t = 0; t < 4; ++t) {
        bank[0][t] = (f32x4){0.f, 0.f, 0.f, 0.f};
        bank[1][t] = (f32x4){0.f, 0.f, 0.f, 0.f};
    }
    int prevCode = 0;

    __syncthreads();                // chunk 0 staged + norms_s/zn_s visible
    int cur = 0;

    for (int cc = 0; cc < NCHUNK; ++cc) {
        // ---- issue next chunk's stage into the OTHER buffer (overlaps compute)
        if (cc + 1 < NCHUNK) {
            const int chn = (cc + 1 + ch0) & (NCHUNK - 1);
            const char* g = (const char*)cbx + (size_t)chn * (2 * PLSTR * 2);
            char* lh = (char*)&bx_s[cur ^ 1][0];
            #pragma unroll
            for (int i = 0; i < 4; ++i) {
                const int off = (w * 4 + i) * 1024 + lane * 16;
                gload_lds16(g + off, lh + off);
            }
        }

        const int ch = (cc + ch0) & (NCHUNK - 1);
        #pragma unroll
        for (int t8 = 0; t8 < 4; ++t8) {               // 4 x 16 = 64 codes/chunk
            const int crow = t8 * 16 + l16;            // chunk-local code row
            const float nv = norms_s[ch * CHUNK + crow];
            const half8 bh0 = *(const half8*)(&bx_s[cur][crow * KDIM + p0]);
            const half8 bh1 = *(const half8*)(&bx_s[cur][crow * KDIM + p1]);
            const half8 bl0 = *(const half8*)(&bx_s[cur][PLSTR + crow * KDIM + p0]);
            const half8 bl1 = *(const half8*)(&bx_s[cur][PLSTR + crow * KDIM + p1]);
            const int code = ch * CHUNK + crow;
            const int bk = t8 & 1, pv = bk ^ 1;

            // track the DEFERRED tile (previous t8) held in bank[pv];
            // independent of bank[bk]'s MFMAs below -> overlaps them
            if (cc + t8 > 0) {
                #pragma unroll
                for (int t = 0; t < 4; ++t)
                    #pragma unroll
                    for (int r = 0; r < 4; ++r) {
                        float d = bank[pv][t][r];
                        bool cnd = d < m1[t][r];
                        m2[t][r] = __builtin_amdgcn_fmed3f(d, m1[t][r], m2[t][r]);
                        m1[t][r] = fminf(m1[t][r], d);
                        i1[t][r] = cnd ? prevCode : i1[t][r];
                    }
            }

            // 3-term hi/lo MFMA: (ah+al)*(bh+bl) ~ ah*bh + al*bh + ah*bl
            // 4 independent 6-chains (one per tile t) -> latency hidden by ILP
            #pragma unroll
            for (int t = 0; t < 4; ++t) {
                f32x4 acc = {nv, nv, nv, nv};
                acc = __builtin_amdgcn_mfma_f32_16x16x32_f16(ah[t][0], bh0, acc, 0, 0, 0);
                acc = __builtin_amdgcn_mfma_f32_16x16x32_f16(al[t][0], bh0, acc, 0, 0, 0);
                acc = __builtin_amdgcn_mfma_f32_16x16x32_f16(ah[t][0], bl0, acc, 0, 0, 0);
                acc = __builtin_amdgcn_mfma_f32_16x16x32_f16(ah[t][1], bh1, acc, 0, 0, 0);
                acc = __builtin_amdgcn_mfma_f32_16x16x32_f16(al[t][1], bh1, acc, 0, 0, 0);
                acc = __builtin_amdgcn_mfma_f32_16x16x32_f16(ah[t][1], bl1, acc, 0, 0, 0);
                bank[bk][t] = acc;
            }
            prevCode = code;
        }

        __syncthreads();   // implicit vmcnt(0): next buffer landed; cur reads done
        cur ^= 1;
    }
    // final deferred tile (last t8=3 wrote bank[1])
    {
        #pragma unroll
        for (int t = 0; t < 4; ++t)
            #pragma unroll
            for (int r = 0; r < 4; ++r) {
                float d = bank[1][t][r];
                bool cnd = d < m1[t][r];
                m2[t][r] = __builtin_amdgcn_fmed3f(d, m1[t][r], m2[t][r]);
                m1[t][r] = fminf(m1[t][r], d);
                i1[t][r] = cnd ? prevCode : i1[t][r];
            }
    }

    // ---- merge across 16 lanes (code residues), first-index ties
    #pragma unroll
    for (int s = 1; s < 16; s <<= 1)
        #pragma unroll
        for (int t = 0; t < 4; ++t)
            #pragma unroll
            for (int r = 0; r < 4; ++r) {
                float o1 = __shfl_xor(m1[t][r], s, 64);
                int   oi = __shfl_xor(i1[t][r], s, 64);
                float o2 = __shfl_xor(m2[t][r], s, 64);
                m2[t][r] = __builtin_amdgcn_fmed3f(m1[t][r], o1, fminf(m2[t][r], o2));
                if (o1 < m1[t][r] || (o1 == m1[t][r] && oi < i1[t][r])) {
                    m1[t][r] = o1; i1[t][r] = oi;
                }
            }

    // ---- owners (l16==0): publish idx, batched flags, loss partial
    float lsum = 0.0f;
    if (l16 == 0) {
        int nf = 0;
        #pragma unroll
        for (int t = 0; t < 4; ++t)
            #pragma unroll
            for (int r = 0; r < 4; ++r) {
                const int ql = 64 * w + t * 16 + quad * 4 + r;
                idx_s[ql] = i1[t][r];
                lsum += m1[t][r] + zn_s[ql];
                nf += (m2[t][r] - m1[t][r] < TAU) ? 1 : 0;
            }
        if (nf) {                      // ONE atomic per flagging owner thread
            int pos = atomicAdd(flag_cnt, nf);
            #pragma unroll
            for (int t = 0; t < 4; ++t)
                #pragma unroll
                for (int r = 0; r < 4; ++r)
                    if (m2[t][r] - m1[t][r] < TAU) {
                        if (pos < FCAP) {
                            flag_q[pos]   = qb + 64 * w + t * 16 + quad * 4 + r;
                            flag_m1[pos]  = m1[t][r];
                            flag_idx[pos] = i1[t][r];
                        }
                        ++pos;
                    }
        }
    }
    #pragma unroll
    for (int s = 1; s < 64; s <<= 1) lsum += __shfl_xor(lsum, s, 64);
    if (lane == 0) wsum_s[w] = lsum;
    __syncthreads();                   // idx_s + wsum_s visible

    // per-block loss partial: plain store, NO global atomic
    if (tid == 0)
        loss_part[blockIdx.x] = wsum_s[0] + wsum_s[1] + wsum_s[2] + wsum_s[3];

    // ---- epilogue: thread tid -> query tid, all 64 channels (coalesced per
    //      channel across the 256 threads)
    {
        const int q   = tid;
        const int idx = idx_s[q];
        const float4* row = (const float4*)(cb + (size_t)idx * KDIM);
        float* op = out + 1 + (size_t)b * CHW + hw0 + q;
        #pragma unroll
        for (int i4 = 0; i4 < 16; ++i4) {
            float4 v = row[i4];
            op[(size_t)(i4 * 4 + 0) * HWD] = v.x;
            op[(size_t)(i4 * 4 + 1) * HWD] = v.y;
            op[(size_t)(i4 * 4 + 2) * HWD] = v.z;
            op[(size_t)(i4 * 4 + 3) * HWD] = v.w;
        }
    }
}

// ---------------- fix: exact fp32 re-rank for flagged queries + finalize ----
// lane = (code-in-pass lane>>2, dim-segment lane&3). Each lane holds 16 z dims
// in registers; cb loads are coalesced 16B chunks; two intra-quad shuffles
// finish each distance; 64 passes x 16 codes = all 1024 codes. (R12-proven.)
__global__ __launch_bounds__(256, 1) void vq_fix(
                       const float* __restrict__ z,
                       const float* __restrict__ cb,
                       float* __restrict__ out,
                       float* __restrict__ loss_adj,
                       const float* __restrict__ loss_part,
                       const int* __restrict__ flag_q,
                       const float* __restrict__ flag_m1,
                       const int* __restrict__ flag_idx,
                       const int* __restrict__ flag_cnt,
                       int* __restrict__ done_cnt) {
    __shared__ float red_s[4];
    __shared__ int   last_s;

    const int w    = threadIdx.x >> 6;
    const int lane = threadIdx.x & 63;
    const int seg  = lane & 3;          // 16-dim segment of the query
    const int cg   = lane >> 2;         // code-in-pass 0..15
    const int gw   = blockIdx.x * 4 + w;
    const int NW   = gridDim.x * 4;

    int n = *flag_cnt;
    if (n > FCAP) n = FCAP;

    for (int f = gw; f < n; f += NW) {
        const int   q   = flag_q[f];
        const float m1o = flag_m1[f];
        const int   io  = flag_idx[f];
        const int   b   = q >> 12;
        const int   hw  = q & 4095;

        // 16 register-resident z dims per lane (segment seg)
        float zq[16];
        float zpart = 0.0f;
        #pragma unroll
        for (int i = 0; i < 16; ++i) {
            zq[i] = z[(size_t)b * CHW + (size_t)(seg * 16 + i) * HWD + hw];
            zpart = fmaf(zq[i], zq[i], zpart);
        }
        float znorm = zpart;
        znorm += __shfl_xor(znorm, 1, 64);
        znorm += __shfl_xor(znorm, 2, 64);   // full ||z||^2 in every lane

        float best = 3.4e38f; int bj = 0;
        #pragma unroll 4
        for (int p = 0; p < 64; ++p) {
            const int j = p * 16 + cg;       // 64 passes x 16 codes = 1024
            const float4* rp = (const float4*)(cb + (size_t)j * KDIM + seg * 16);
            float d = 0.0f;
            #pragma unroll
            for (int q4 = 0; q4 < 4; ++q4) {
                float4 v = rp[q4];
                float t0 = zq[q4 * 4 + 0] - v.x;
                float t1 = zq[q4 * 4 + 1] - v.y;
                float t2 = zq[q4 * 4 + 2] - v.z;
                float t3 = zq[q4 * 4 + 3] - v.w;
                d = fmaf(t0, t0, d); d = fmaf(t1, t1, d);
                d = fmaf(t2, t2, d); d = fmaf(t3, t3, d);
            }
            d += __shfl_xor(d, 1, 64);
            d += __shfl_xor(d, 2, 64);       // full distance of code j (quad)
            if (d < best) { best = d; bj = j; }  // j ascends per lane: first-min
        }
        // reduce across 16 code-groups (quad lanes identical): steps 4..32
        #pragma unroll
        for (int s = 4; s < 64; s <<= 1) {
            float ob = __shfl_xor(best, s, 64);
            int   oj = __shfl_xor(bj, s, 64);
            if (ob < best || (ob == best && oj < bj)) { best = ob; bj = oj; }
        }
        if (bj != io) {
            out[1 + (size_t)b * CHW + (size_t)lane * HWD + hw] = cb[(size_t)bj * KDIM + lane];
            if (lane == 0) atomicAdd(loss_adj, best - (m1o + znorm));
        }
    }

    __syncthreads();
    if (threadIdx.x == 0) {
        __threadfence();
        last_s = (atomicAdd(done_cnt, 1) == (int)gridDim.x - 1) ? 1 : 0;
    }
    __syncthreads();

    if (last_s) {
        // all other blocks' loss_adj atomics + vq_main partials are visible
        float s = 0.0f;
        for (int i = threadIdx.x; i < NBLK; i += 256) s += loss_part[i];
        #pragma unroll
        for (int sh = 1; sh < 64; sh <<= 1) s += __shfl_xor(s, sh, 64);
        if (lane == 0) red_s[w] = s;
        __syncthreads();
        if (threadIdx.x == 0) {
            float L = red_s[0] + red_s[1] + red_s[2] + red_s[3]
                    + atomicAdd(loss_adj, 0.0f);
            out[0] = 1.25f * L / TOTALF;
        }
    }
}

extern "C" void kernel_launch(void* const* d_in, const int* in_sizes, int n_in,
                              void* d_out, int out_size, void* d_ws, size_t ws_size,
                              hipStream_t stream) {
    const float* z  = (const float*)d_in[0];
    const float* cb = (const float*)d_in[1];
    float* out      = (float*)d_out;
    char*  ws       = (char*)d_ws;

    float*          loss_adj  = (float*)(ws + 0);
    int*            flag_cnt  = (int*)(ws + 4);
    int*            done_cnt  = (int*)(ws + 8);
    float*          loss_part = (float*)(ws + 128);
    float*          norms     = (float*)(ws + 4224);
    unsigned short* cbx       = (unsigned short*)(ws + 8320);
    int*            flag_q    = (int*)(ws + 270464);
    float*          flag_m1   = (float*)(ws + 336000);
    int*            flag_idx  = (int*)(ws + 401536);

    vq_prep<<<dim3(16), dim3(256), 0, stream>>>(cb, norms, cbx,
                                                loss_adj, flag_cnt, done_cnt);

    vq_main<<<dim3(NBLK), dim3(256), 0, stream>>>(z, cb, cbx, norms, out,
                                                  loss_part, flag_q, flag_m1,
                                                  flag_idx, flag_cnt);

    vq_fix<<<dim3(256), dim3(256), 0, stream>>>(z, cb, out, loss_adj, loss_part,
                                                flag_q, flag_m1, flag_idx,
                                                flag_cnt, done_cnt);
}

// Round 14
// 258.457 us; speedup vs baseline: 1.7762x; 1.7762x over previous
//
#include <hip/hip_runtime.h>

// VQ-VAE VectorQuantizer: fp16 hi/lo 3-term MFMA distance + exact fp32 fallback.
// z: (32,64,64,64) NCHW fp32; codebook: (1024,64) fp32.
// d_out: [0]=loss, [1..]=z_q (NCHW).
//
// R22 (from R21 post-mortem): (256,4) squeezed VGPR to 64 vs ~116 demand ->
// spill catastrophe (FETCH 475MB / WRITE 444MB, 418us). THIRD time this trap
// fired (R9, R17, R21). Rule: (256,4)=>64 cap, (256,3)=>~170, (256,2)=>~256.
// launch_bounds sets the ALLOCATOR target; actual occupancy is resource-
// determined at dispatch. R15's identical body measured VGPR=116 <= 128 (the
// 4-waves/SIMD threshold, m69) and CHUNK=64 LDS = 39424B -> 4 x 39424 =
// 157696 <= 163840: 4 blocks/CU fits BOTH budgets with the natural
// allocation. So: ONE token changed vs R21 -- (256,4) -> (256,3). Compiler
// allocates its natural ~116 (no squeeze), hardware co-schedules 4 blocks/CU
// (4 waves/SIMD, 2x R15's occupancy).
// Everything else VERBATIM R21/R15: CHUNK 64 combined hi|lo chunk-major,
// 512 blocks x 256 queries, 4 t-tiles/wave, 3-term fp16 hi/lo (err~1e-4,
// TAU=1e-3 -> n~250), batched flag atomics, per-block loss partials,
// R12-proven vq_fix + done_cnt finalize.

#define CB_N   1024
#define KDIM   64
#define HWD    4096
#define CHW    (KDIM * HWD)
#define NQ     131072
#define TOTALF 8388608.0f
#define TAU    1.0e-3f
#define FCAP   16384
#define CHUNK  64             // codes per LDS chunk
#define NCHUNK (CB_N / CHUNK) // 16
#define PLSTR  (CHUNK * KDIM) // u16 stride between hi and lo planes (4096)
#define NBLK   512            // vq_main grid

typedef __attribute__((ext_vector_type(8))) _Float16 half8;
typedef __attribute__((ext_vector_type(4))) float    f32x4;

// async 16B/lane global->LDS copy (wave-uniform contiguous; m97 pattern)
__device__ __forceinline__ void gload_lds16(const void* g, void* l) {
    __builtin_amdgcn_global_load_lds(
        (const __attribute__((address_space(1))) unsigned int*)g,
        (__attribute__((address_space(3))) unsigned int*)l,
        16, 0, 0);
}

// ---------- ws layout (byte offsets) ----------
// 0: loss_adj  4: flag_cnt  8: done_cnt
// 128:    loss_part f32[512]
// 4224:   norms     f32[1024]
// 8320:   cbx       u16[16][2][64][64]  (fp16 hi|lo, chunk-major, rotate-swz)
// 270464: flag_q i32[FCAP]  336000: flag_m1 f32[FCAP]  401536: flag_idx i32[FCAP]

// ---------------- prep: fp16 hi/lo split, combined layout, norms ------------
__global__ void vq_prep(const float* __restrict__ cb,
                        float* __restrict__ norms,
                        unsigned short* __restrict__ cbx,
                        float* __restrict__ loss_adj,
                        int* __restrict__ flag_cnt,
                        int* __restrict__ done_cnt) {
    const int tid = blockIdx.x * 256 + threadIdx.x;
    if (tid == 0) *loss_adj = 0.0f;
    if (tid == 1) *flag_cnt = 0;
    if (tid == 2) *done_cnt = 0;
    const int j  = tid >> 2;
    const int s2 = tid & 3;

    const int chunk = j >> 6;         // code's chunk (64 codes each)
    const int row   = j & 63;         // row within chunk
    unsigned short* hi = cbx + ((size_t)chunk * 2 + 0) * PLSTR + row * KDIM;
    unsigned short* lo = cbx + ((size_t)chunk * 2 + 1) * PLSTR + row * KDIM;

    const float4* r4 = (const float4*)(cb + (size_t)j * KDIM);
    float s_norm = 0.0f;
    #pragma unroll
    for (int seg8 = 0; seg8 < 2; ++seg8) {
        const int s = s2 * 2 + seg8;
        float4 v0 = r4[s * 2 + 0];
        float4 v1 = r4[s * 2 + 1];
        float e[8] = {v0.x, v0.y, v0.z, v0.w, v1.x, v1.y, v1.z, v1.w};
        unsigned hh[4], ll[4];
        #pragma unroll
        for (int c = 0; c < 8; ++c) {
            float x = e[c];
            s_norm = fmaf(x, x, s_norm);
            union { _Float16 h; unsigned short u; } ch, cl;
            ch.h = (_Float16)x;                       // RNE fp16 hi
            cl.h = (_Float16)(x - (float)ch.h);       // RNE fp16 lo
            if ((c & 1) == 0) { hh[c >> 1] = ch.u;               ll[c >> 1] = cl.u; }
            else              { hh[c >> 1] |= ((unsigned)ch.u) << 16;
                                ll[c >> 1] |= ((unsigned)cl.u) << 16; }
        }
        const int p = (s + j) & 7;                    // bank-deconflict rotate
        *(uint4*)(hi + p * 8) = make_uint4(hh[0], hh[1], hh[2], hh[3]);
        *(uint4*)(lo + p * 8) = make_uint4(ll[0], ll[1], ll[2], ll[3]);
    }
    s_norm += __shfl_xor(s_norm, 1, 64);
    s_norm += __shfl_xor(s_norm, 2, 64);
    if (s2 == 0) norms[j] = s_norm;
}

// ---------------- main ------------------------------------------------------
__global__ __launch_bounds__(256, 3) void vq_main(
        const float* __restrict__ z,
        const float* __restrict__ cb,
        const unsigned short* __restrict__ cbx,
        const float* __restrict__ norms,
        float* __restrict__ out,
        float* __restrict__ loss_part,
        int* __restrict__ flag_q,
        float* __restrict__ flag_m1,
        int* __restrict__ flag_idx,
        int* __restrict__ flag_cnt) {
    __shared__ float          norms_s[CB_N];             // 4 KB
    __shared__ unsigned short bx_s[2][2 * PLSTR];        // 2 x 16 KB (dbuf, hi|lo)
    __shared__ float          zn_s[256];
    __shared__ int            idx_s[256];
    __shared__ float          wsum_s[4];

    const int tid  = threadIdx.x;
    const int w    = tid >> 6;
    const int lane = tid & 63;
    const int quad = lane >> 4;
    const int l16  = lane & 15;
    const int qb   = blockIdx.x * 256;     // block's 256 queries (same batch b)
    const int b    = qb >> 12;
    const int hw0  = qb & 4095;
    const int ch0  = blockIdx.x & (NCHUNK - 1);   // de-phase chunk start

    // ---- issue stage of chunk 0 FIRST (flies under the z-read prologue)
    {
        const char* g = (const char*)cbx + (size_t)ch0 * (2 * PLSTR * 2);
        #pragma unroll
        for (int i = 0; i < 4; ++i) {
            const int off = (w * 4 + i) * 1024 + lane * 16;
            gload_lds16(g + off, (char*)&bx_s[0][0] + off);
        }
    }

    // ---- stage all code norms into LDS
    *(float4*)(norms_s + tid * 4) = *(const float4*)(norms + tid * 4);

    // ---- stage A-frags: wave w owns queries [64w, 64w+64); 4 tiles of 16.
    const float* zbase = z + (size_t)b * CHW + hw0 + 64 * w;
    half8 ah[4][2], al[4][2];
    float znp[4] = {0.f, 0.f, 0.f, 0.f};
    #pragma unroll
    for (int t = 0; t < 4; ++t)
        #pragma unroll
        for (int ks = 0; ks < 2; ++ks)
            #pragma unroll
            for (int j = 0; j < 8; ++j) {
                float v = zbase[(size_t)(ks * 32 + quad * 8 + j) * HWD + t * 16 + l16];
                znp[t] = fmaf(v, v, znp[t]);
                float s = -2.0f * v;
                _Float16 h = (_Float16)s;             // RNE fp16 hi
                ah[t][ks][j] = h;
                al[t][ks][j] = (_Float16)(s - (float)h);   // lo
            }
    #pragma unroll
    for (int t = 0; t < 4; ++t) {
        znp[t] += __shfl_xor(znp[t], 16, 64);
        znp[t] += __shfl_xor(znp[t], 32, 64);
    }
    if (lane < 16)
        #pragma unroll
        for (int t = 0; t < 4; ++t)
            zn_s[64 * w + t * 16 + lane] = znp[t];

    float m1[4][4], m2[4][4];
    int   i1[4][4];
    #pragma unroll
    for (int t = 0; t < 4; ++t)
        #pragma unroll
        for (int r = 0; r < 4; ++r) { m1[t][r] = 3.4e38f; m2[t][r] = 3.4e38f; i1[t][r] = 0; }

    // loop-invariant swizzled segment offsets (ks=0 / ks=1)
    const int p0 = ((quad + l16) & 7) * 8;
    const int p1 = ((4 + quad + l16) & 7) * 8;

    f32x4 bank[2][4];               // [tile-parity][t] -- deferred tracking
    #pragma unroll
    for (int t = 0; t < 4; ++t) {
        bank[0][t] = (f32x4){0.f, 0.f, 0.f, 0.f};
        bank[1][t] = (f32x4){0.f, 0.f, 0.f, 0.f};
    }
    int prevCode = 0;

    __syncthreads();                // chunk 0 staged + norms_s/zn_s visible
    int cur = 0;

    for (int cc = 0; cc < NCHUNK; ++cc) {
        // ---- issue next chunk's stage into the OTHER buffer (overlaps compute)
        if (cc + 1 < NCHUNK) {
            const int chn = (cc + 1 + ch0) & (NCHUNK - 1);
            const char* g = (const char*)cbx + (size_t)chn * (2 * PLSTR * 2);
            char* lh = (char*)&bx_s[cur ^ 1][0];
            #pragma unroll
            for (int i = 0; i < 4; ++i) {
                const int off = (w * 4 + i) * 1024 + lane * 16;
                gload_lds16(g + off, lh + off);
            }
        }

        const int ch = (cc + ch0) & (NCHUNK - 1);
        #pragma unroll
        for (int t8 = 0; t8 < 4; ++t8) {               // 4 x 16 = 64 codes/chunk
            const int crow = t8 * 16 + l16;            // chunk-local code row
            const float nv = norms_s[ch * CHUNK + crow];
            const half8 bh0 = *(const half8*)(&bx_s[cur][crow * KDIM + p0]);
            const half8 bh1 = *(const half8*)(&bx_s[cur][crow * KDIM + p1]);
            const half8 bl0 = *(const half8*)(&bx_s[cur][PLSTR + crow * KDIM + p0]);
            const half8 bl1 = *(const half8*)(&bx_s[cur][PLSTR + crow * KDIM + p1]);
            const int code = ch * CHUNK + crow;
            const int bk = t8 & 1, pv = bk ^ 1;

            // track the DEFERRED tile (previous t8) held in bank[pv];
            // independent of bank[bk]'s MFMAs below -> overlaps them
            if (cc + t8 > 0) {
                #pragma unroll
                for (int t = 0; t < 4; ++t)
                    #pragma unroll
                    for (int r = 0; r < 4; ++r) {
                        float d = bank[pv][t][r];
                        bool cnd = d < m1[t][r];
                        m2[t][r] = __builtin_amdgcn_fmed3f(d, m1[t][r], m2[t][r]);
                        m1[t][r] = fminf(m1[t][r], d);
                        i1[t][r] = cnd ? prevCode : i1[t][r];
                    }
            }

            // 3-term hi/lo MFMA: (ah+al)*(bh+bl) ~ ah*bh + al*bh + ah*bl
            // 4 independent 6-chains (one per tile t) -> latency hidden by ILP
            #pragma unroll
            for (int t = 0; t < 4; ++t) {
                f32x4 acc = {nv, nv, nv, nv};
                acc = __builtin_amdgcn_mfma_f32_16x16x32_f16(ah[t][0], bh0, acc, 0, 0, 0);
                acc = __builtin_amdgcn_mfma_f32_16x16x32_f16(al[t][0], bh0, acc, 0, 0, 0);
                acc = __builtin_amdgcn_mfma_f32_16x16x32_f16(ah[t][0], bl0, acc, 0, 0, 0);
                acc = __builtin_amdgcn_mfma_f32_16x16x32_f16(ah[t][1], bh1, acc, 0, 0, 0);
                acc = __builtin_amdgcn_mfma_f32_16x16x32_f16(al[t][1], bh1, acc, 0, 0, 0);
                acc = __builtin_amdgcn_mfma_f32_16x16x32_f16(ah[t][1], bl1, acc, 0, 0, 0);
                bank[bk][t] = acc;
            }
            prevCode = code;
        }

        __syncthreads();   // implicit vmcnt(0): next buffer landed; cur reads done
        cur ^= 1;
    }
    // final deferred tile (last t8=3 wrote bank[1])
    {
        #pragma unroll
        for (int t = 0; t < 4; ++t)
            #pragma unroll
            for (int r = 0; r < 4; ++r) {
                float d = bank[1][t][r];
                bool cnd = d < m1[t][r];
                m2[t][r] = __builtin_amdgcn_fmed3f(d, m1[t][r], m2[t][r]);
                m1[t][r] = fminf(m1[t][r], d);
                i1[t][r] = cnd ? prevCode : i1[t][r];
            }
    }

    // ---- merge across 16 lanes (code residues), first-index ties
    #pragma unroll
    for (int s = 1; s < 16; s <<= 1)
        #pragma unroll
        for (int t = 0; t < 4; ++t)
            #pragma unroll
            for (int r = 0; r < 4; ++r) {
                float o1 = __shfl_xor(m1[t][r], s, 64);
                int   oi = __shfl_xor(i1[t][r], s, 64);
                float o2 = __shfl_xor(m2[t][r], s, 64);
                m2[t][r] = __builtin_amdgcn_fmed3f(m1[t][r], o1, fminf(m2[t][r], o2));
                if (o1 < m1[t][r] || (o1 == m1[t][r] && oi < i1[t][r])) {
                    m1[t][r] = o1; i1[t][r] = oi;
                }
            }

    // ---- owners (l16==0): publish idx, batched flags, loss partial
    float lsum = 0.0f;
    if (l16 == 0) {
        int nf = 0;
        #pragma unroll
        for (int t = 0; t < 4; ++t)
            #pragma unroll
            for (int r = 0; r < 4; ++r) {
                const int ql = 64 * w + t * 16 + quad * 4 + r;
                idx_s[ql] = i1[t][r];
                lsum += m1[t][r] + zn_s[ql];
                nf += (m2[t][r] - m1[t][r] < TAU) ? 1 : 0;
            }
        if (nf) {                      // ONE atomic per flagging owner thread
            int pos = atomicAdd(flag_cnt, nf);
            #pragma unroll
            for (int t = 0; t < 4; ++t)
                #pragma unroll
                for (int r = 0; r < 4; ++r)
                    if (m2[t][r] - m1[t][r] < TAU) {
                        if (pos < FCAP) {
                            flag_q[pos]   = qb + 64 * w + t * 16 + quad * 4 + r;
                            flag_m1[pos]  = m1[t][r];
                            flag_idx[pos] = i1[t][r];
                        }
                        ++pos;
                    }
        }
    }
    #pragma unroll
    for (int s = 1; s < 64; s <<= 1) lsum += __shfl_xor(lsum, s, 64);
    if (lane == 0) wsum_s[w] = lsum;
    __syncthreads();                   // idx_s + wsum_s visible

    // per-block loss partial: plain store, NO global atomic
    if (tid == 0)
        loss_part[blockIdx.x] = wsum_s[0] + wsum_s[1] + wsum_s[2] + wsum_s[3];

    // ---- epilogue: thread tid -> query tid, all 64 channels (coalesced per
    //      channel across the 256 threads)
    {
        const int q   = tid;
        const int idx = idx_s[q];
        const float4* row = (const float4*)(cb + (size_t)idx * KDIM);
        float* op = out + 1 + (size_t)b * CHW + hw0 + q;
        #pragma unroll
        for (int i4 = 0; i4 < 16; ++i4) {
            float4 v = row[i4];
            op[(size_t)(i4 * 4 + 0) * HWD] = v.x;
            op[(size_t)(i4 * 4 + 1) * HWD] = v.y;
            op[(size_t)(i4 * 4 + 2) * HWD] = v.z;
            op[(size_t)(i4 * 4 + 3) * HWD] = v.w;
        }
    }
}

// ---------------- fix: exact fp32 re-rank for flagged queries + finalize ----
// lane = (code-in-pass lane>>2, dim-segment lane&3). Each lane holds 16 z dims
// in registers; cb loads are coalesced 16B chunks; two intra-quad shuffles
// finish each distance; 64 passes x 16 codes = all 1024 codes. (R12-proven.)
__global__ __launch_bounds__(256, 1) void vq_fix(
                       const float* __restrict__ z,
                       const float* __restrict__ cb,
                       float* __restrict__ out,
                       float* __restrict__ loss_adj,
                       const float* __restrict__ loss_part,
                       const int* __restrict__ flag_q,
                       const float* __restrict__ flag_m1,
                       const int* __restrict__ flag_idx,
                       const int* __restrict__ flag_cnt,
                       int* __restrict__ done_cnt) {
    __shared__ float red_s[4];
    __shared__ int   last_s;

    const int w    = threadIdx.x >> 6;
    const int lane = threadIdx.x & 63;
    const int seg  = lane & 3;          // 16-dim segment of the query
    const int cg   = lane >> 2;         // code-in-pass 0..15
    const int gw   = blockIdx.x * 4 + w;
    const int NW   = gridDim.x * 4;

    int n = *flag_cnt;
    if (n > FCAP) n = FCAP;

    for (int f = gw; f < n; f += NW) {
        const int   q   = flag_q[f];
        const float m1o = flag_m1[f];
        const int   io  = flag_idx[f];
        const int   b   = q >> 12;
        const int   hw  = q & 4095;

        // 16 register-resident z dims per lane (segment seg)
        float zq[16];
        float zpart = 0.0f;
        #pragma unroll
        for (int i = 0; i < 16; ++i) {
            zq[i] = z[(size_t)b * CHW + (size_t)(seg * 16 + i) * HWD + hw];
            zpart = fmaf(zq[i], zq[i], zpart);
        }
        float znorm = zpart;
        znorm += __shfl_xor(znorm, 1, 64);
        znorm += __shfl_xor(znorm, 2, 64);   // full ||z||^2 in every lane

        float best = 3.4e38f; int bj = 0;
        #pragma unroll 4
        for (int p = 0; p < 64; ++p) {
            const int j = p * 16 + cg;       // 64 passes x 16 codes = 1024
            const float4* rp = (const float4*)(cb + (size_t)j * KDIM + seg * 16);
            float d = 0.0f;
            #pragma unroll
            for (int q4 = 0; q4 < 4; ++q4) {
                float4 v = rp[q4];
                float t0 = zq[q4 * 4 + 0] - v.x;
                float t1 = zq[q4 * 4 + 1] - v.y;
                float t2 = zq[q4 * 4 + 2] - v.z;
                float t3 = zq[q4 * 4 + 3] - v.w;
                d = fmaf(t0, t0, d); d = fmaf(t1, t1, d);
                d = fmaf(t2, t2, d); d = fmaf(t3, t3, d);
            }
            d += __shfl_xor(d, 1, 64);
            d += __shfl_xor(d, 2, 64);       // full distance of code j (quad)
            if (d < best) { best = d; bj = j; }  // j ascends per lane: first-min
        }
        // reduce across 16 code-groups (quad lanes identical): steps 4..32
        #pragma unroll
        for (int s = 4; s < 64; s <<= 1) {
            float ob = __shfl_xor(best, s, 64);
            int   oj = __shfl_xor(bj, s, 64);
            if (ob < best || (ob == best && oj < bj)) { best = ob; bj = oj; }
        }
        if (bj != io) {
            out[1 + (size_t)b * CHW + (size_t)lane * HWD + hw] = cb[(size_t)bj * KDIM + lane];
            if (lane == 0) atomicAdd(loss_adj, best - (m1o + znorm));
        }
    }

    __syncthreads();
    if (threadIdx.x == 0) {
        __threadfence();
        last_s = (atomicAdd(done_cnt, 1) == (int)gridDim.x - 1) ? 1 : 0;
    }
    __syncthreads();

    if (last_s) {
        // all other blocks' loss_adj atomics + vq_main partials are visible
        float s = 0.0f;
        for (int i = threadIdx.x; i < NBLK; i += 256) s += loss_part[i];
        #pragma unroll
        for (int sh = 1; sh < 64; sh <<= 1) s += __shfl_xor(s, sh, 64);
        if (lane == 0) red_s[w] = s;
        __syncthreads();
        if (threadIdx.x == 0) {
            float L = red_s[0] + red_s[1] + red_s[2] + red_s[3]
                    + atomicAdd(loss_adj, 0.0f);
            out[0] = 1.25f * L / TOTALF;
        }
    }
}

extern "C" void kernel_launch(void* const* d_in, const int* in_sizes, int n_in,
                              void* d_out, int out_size, void* d_ws, size_t ws_size,
                              hipStream_t stream) {
    const float* z  = (const float*)d_in[0];
    const float* cb = (const float*)d_in[1];
    float* out      = (float*)d_out;
    char*  ws       = (char*)d_ws;

    float*          loss_adj  = (float*)(ws + 0);
    int*            flag_cnt  = (int*)(ws + 4);
    int*            done_cnt  = (int*)(ws + 8);
    float*          loss_part = (float*)(ws + 128);
    float*          norms     = (float*)(ws + 4224);
    unsigned short* cbx       = (unsigned short*)(ws + 8320);
    int*            flag_q    = (int*)(ws + 270464);
    float*          flag_m1   = (float*)(ws + 336000);
    int*            flag_idx  = (int*)(ws + 401536);

    vq_prep<<<dim3(16), dim3(256), 0, stream>>>(cb, norms, cbx,
                                                loss_adj, flag_cnt, done_cnt);

    vq_main<<<dim3(NBLK), dim3(256), 0, stream>>>(z, cb, cbx, norms, out,
                                                  loss_part, flag_q, flag_m1,
                                                  flag_idx, flag_cnt);

    vq_fix<<<dim3(256), dim3(256), 0, stream>>>(z, cb, out, loss_adj, loss_part,
                                                flag_q, flag_m1, flag_idx,
                                                flag_cnt, done_cnt);
}